// Round 1
// baseline (369.209 us; speedup 1.0000x reference)
//
#include <hip/hip_runtime.h>
#include <hip/hip_bf16.h>

// CentralSpecificModel: per-species 2-layer MLP (256 -> 1024 -> 256), 4 species,
// N=65536 rows, fp32 in/out. Strategy: bucket rows by species, then one fused
// kernel per 64-row single-species tile does GEMM1+silu+GEMM2 with bf16 MFMA
// (16x16x32). Weights are pre-converted to bf16 in exact B-fragment order so
// fragments load straight from global (L2-resident, 4 MB total) - no LDS
// staging for B, no inter-wave read redundancy. h never touches HBM.

#define N_ATOMS 65536
#define D_IN 256
#define D_HID 1024
#define D_OUT 256
#define TPS 1024   // max 64-row tiles per species (worst case all rows one species)

typedef __attribute__((ext_vector_type(8))) short short8;
typedef __attribute__((ext_vector_type(4))) float float4e;

// ws layout (bytes):
//   [0, 16)            cnt[4]
//   [256, 1048832)     bucket[4][65536] int  (row indices per species)
//   [1048832, 3145984) W1 swizzled bf16 fragments (4*256*1024)
//   [3145984, 5243136) W2 swizzled bf16 fragments (4*1024*256)
#define WS_BUCKET_OFF 256
#define WS_W1_OFF 1048832
#define WS_W2_OFF 3145984

__device__ __forceinline__ short f2bf(float f) {
  unsigned u = __builtin_bit_cast(unsigned, f);
  unsigned r = (u + 0x7FFFu + ((u >> 16) & 1u)) >> 16;   // round-to-nearest-even
  return (short)r;
}

// Swizzle W1/W2 fp32 -> bf16 MFMA B-fragment order, and zero cnt.
// B-frag (16x16x32): lane l holds B[k0 + 8*(l>>4) + j][nt*16 + (l&15)], j=0..7,
// stored so each lane's 8 elems are 16B-contiguous and lanes are consecutive.
__global__ void prep_kernel(const float* __restrict__ W1, const float* __restrict__ W2,
                            short* __restrict__ w1sw, short* __restrict__ w2sw,
                            int* __restrict__ cnt) {
  int gid = blockIdx.x * 256 + threadIdx.x;   // 262144 threads
  if (gid < 4) cnt[gid] = 0;
  int lane = gid & 63;
  int lr = lane & 15;
  int lk = (lane >> 4) * 8;
  if (gid < 131072) {            // W1: [4][256][1024], NT=64, KS=8
    int ks = (gid >> 6) & 7;
    int nt = (gid >> 9) & 63;
    int s  = gid >> 15;
    const float* src = W1 + ((size_t)(s * 256 + ks * 32 + lk)) * 1024 + nt * 16 + lr;
    short8 v;
    for (int j = 0; j < 8; ++j) v[j] = f2bf(src[(size_t)j * 1024]);
    *(short8*)(w1sw + (size_t)gid * 8) = v;
  } else {                       // W2: [4][1024][256], NT=16, KS=32
    int g = gid - 131072;
    int kt = (g >> 6) & 31;
    int nt = (g >> 11) & 15;
    int s  = g >> 15;
    const float* src = W2 + ((size_t)(s * 1024 + kt * 32 + lk)) * 256 + nt * 16 + lr;
    short8 v;
    for (int j = 0; j < 8; ++j) v[j] = f2bf(src[(size_t)j * 256]);
    *(short8*)(w2sw + (size_t)g * 8) = v;
  }
}

// Bucket rows by species. Wave-aggregated: 4 atomics per wave, not 64.
__global__ void count_fill_kernel(const int* __restrict__ species,
                                  int* __restrict__ cnt, int* __restrict__ bucket) {
  int i = blockIdx.x * 256 + threadIdx.x;
  int s = species[i] & 3;
  int lane = threadIdx.x & 63;
  for (int ss = 0; ss < 4; ++ss) {
    unsigned long long mask = __ballot(s == ss);
    if (s == ss) {
      int rank = __popcll(mask & ((1ull << lane) - 1ull));
      int leader = __ffsll((long long)mask) - 1;
      int base = 0;
      if (lane == leader) base = atomicAdd(&cnt[ss], __popcll(mask));
      base = __shfl(base, leader);
      bucket[ss * N_ATOMS + base + rank] = i;
    }
  }
}

// Fused per-tile MLP. Block = 256 threads (4 waves), tile = 64 rows.
// LDS: Xs 64x256 bf16 (stride 264: +8 pad kills the 512B bank stride),
//      Hs 64x128 bf16 (stride 136). Total 50 KB static.
// Per hid-chunk c (8 chunks of 128):
//   GEMM1: wave covers all 64 rows (4 rt) x 32 hid cols (2 ct); K=256 (8 ksteps)
//   silu -> Hs; barrier
//   GEMM2: wave covers all 64 rows x 64 out cols (4 ct); K=128 (4 ksteps), acc in regs
__global__ __launch_bounds__(256) void fused_kernel(
    const float* __restrict__ x, const int* __restrict__ cntArr,
    const int* __restrict__ bucket, const short* __restrict__ w1sw,
    const short* __restrict__ w2sw, const float* __restrict__ b1,
    const float* __restrict__ b2, float* __restrict__ out) {
  int s = blockIdx.x >> 10;         // TPS = 1024
  int t = blockIdx.x & (TPS - 1);
  int cnt = cntArr[s];
  int r0 = t * 64;
  if (r0 >= cnt) return;
  int nrows = min(64, cnt - r0);
  const int* buck = bucket + s * N_ATOMS + r0;

  __shared__ short Xs[64 * 264];
  __shared__ short Hs[64 * 136];

  int tid = threadIdx.x;

  // Stage gathered x tile -> bf16 LDS. 2048 8-elem groups / 256 threads.
  for (int i = 0; i < 8; ++i) {
    int id = tid + i * 256;
    int r = id >> 5;          // row 0..63
    int g = id & 31;          // 8-float group
    short8 v = {};
    if (r < nrows) {
      const float4* src = (const float4*)(x + (size_t)buck[r] * D_IN + g * 8);
      float4 f0 = src[0];
      float4 f1 = src[1];
      v[0] = f2bf(f0.x); v[1] = f2bf(f0.y); v[2] = f2bf(f0.z); v[3] = f2bf(f0.w);
      v[4] = f2bf(f1.x); v[5] = f2bf(f1.y); v[6] = f2bf(f1.z); v[7] = f2bf(f1.w);
    }
    *(short8*)(Xs + r * 264 + g * 8) = v;
  }
  __syncthreads();

  int lane = tid & 63;
  int wid = tid >> 6;
  int lr = lane & 15;          // A row / B,C col within 16-tile
  int lk = (lane >> 4) * 8;    // k base within 32-kstep
  int lq = (lane >> 4) * 4;    // C/D row base

  float4e accY[4][4] = {};     // 64 rows x 64 out cols per wave -> 64 VGPR

  for (int c = 0; c < 8; ++c) {
    // ---- GEMM1: H[64 x 128] chunk = Xs @ W1[:, c*128 .. c*128+128) ----
    float4e acc1[4][2] = {};
    for (int ks = 0; ks < 8; ++ks) {
      short8 a[4], b[2];
      for (int rt = 0; rt < 4; ++rt)
        a[rt] = *(const short8*)(Xs + (rt * 16 + lr) * 264 + ks * 32 + lk);
      for (int ct = 0; ct < 2; ++ct) {
        int nt = c * 8 + wid * 2 + ct;   // global W1 n-tile
        b[ct] = *(const short8*)(w1sw + ((size_t)((s * 64 + nt) * 8 + ks) * 64 + lane) * 8);
      }
      for (int rt = 0; rt < 4; ++rt)
        for (int ct = 0; ct < 2; ++ct)
          acc1[rt][ct] = __builtin_amdgcn_mfma_f32_16x16x32_bf16(a[rt], b[ct], acc1[rt][ct], 0, 0, 0);
    }
    // ---- bias + silu -> Hs (bf16) ----
    for (int ct = 0; ct < 2; ++ct) {
      int nloc = wid * 32 + ct * 16 + lr;              // 0..127 within chunk
      float bias = b1[s * D_HID + c * 128 + nloc];
      for (int rt = 0; rt < 4; ++rt) {
        float4e v4 = acc1[rt][ct];
        for (int q = 0; q < 4; ++q) {
          float pre = v4[q] + bias;
          float val = pre / (1.0f + __expf(-pre));     // silu
          Hs[(rt * 16 + lq + q) * 136 + nloc] = f2bf(val);
        }
      }
    }
    __syncthreads();
    // ---- GEMM2 partial: accY += H_chunk @ W2[c*128 .. , :] ----
    for (int ks = 0; ks < 4; ++ks) {
      short8 a[4], b[4];
      for (int rt = 0; rt < 4; ++rt)
        a[rt] = *(const short8*)(Hs + (rt * 16 + lr) * 136 + ks * 32 + lk);
      for (int ct = 0; ct < 4; ++ct) {
        int nt = wid * 4 + ct;
        int kt = c * 4 + ks;
        b[ct] = *(const short8*)(w2sw + ((size_t)((s * 16 + nt) * 32 + kt) * 64 + lane) * 8);
      }
      for (int rt = 0; rt < 4; ++rt)
        for (int ct = 0; ct < 4; ++ct)
          accY[rt][ct] = __builtin_amdgcn_mfma_f32_16x16x32_bf16(a[rt], b[ct], accY[rt][ct], 0, 0, 0);
    }
    __syncthreads();   // protect Hs before next chunk's writes
  }

  // ---- epilogue: scatter y + b2 to original rows ----
  for (int ct = 0; ct < 4; ++ct) {
    int n = wid * 64 + ct * 16 + lr;
    float bias = b2[s * D_OUT + n];
    for (int rt = 0; rt < 4; ++rt) {
      for (int q = 0; q < 4; ++q) {
        int r = rt * 16 + lq + q;
        if (r < nrows)
          out[(size_t)buck[r] * D_OUT + n] = accY[rt][ct][q] + bias;
      }
    }
  }
}

extern "C" void kernel_launch(void* const* d_in, const int* in_sizes, int n_in,
                              void* d_out, int out_size, void* d_ws, size_t ws_size,
                              hipStream_t stream) {
  const float* x  = (const float*)d_in[0];
  const int* spc  = (const int*)d_in[1];
  const float* W1 = (const float*)d_in[2];
  const float* b1 = (const float*)d_in[3];
  const float* W2 = (const float*)d_in[4];
  const float* b2 = (const float*)d_in[5];
  float* out = (float*)d_out;

  int*   cnt    = (int*)d_ws;
  int*   bucket = (int*)((char*)d_ws + WS_BUCKET_OFF);
  short* w1sw   = (short*)((char*)d_ws + WS_W1_OFF);
  short* w2sw   = (short*)((char*)d_ws + WS_W2_OFF);

  prep_kernel<<<1024, 256, 0, stream>>>(W1, W2, w1sw, w2sw, cnt);
  count_fill_kernel<<<N_ATOMS / 256, 256, 0, stream>>>(spc, cnt, bucket);
  fused_kernel<<<4 * TPS, 256, 0, stream>>>(x, cnt, bucket, w1sw, w2sw, b1, b2, out);
}

// Round 2
// 255.773 us; speedup vs baseline: 1.4435x; 1.4435x over previous
//
#include <hip/hip_runtime.h>
#include <hip/hip_bf16.h>

// CentralSpecificModel: per-species 2-layer MLP (256 -> 1024 -> 256), 4 species,
// N=65536 rows, fp32 in/out. Bucket rows by species; fused per-64-row-tile
// kernel does GEMM1+silu+GEMM2 with bf16 MFMA (16x16x32). Weights pre-swizzled
// to exact B-fragment order -> fragments load straight from global (L2-resident).
// R2: batched B-frag prefetch (16 at a time, needs launch_bounds(256,2) register
// budget), double-buffered Hs (1 barrier per chunk instead of 2), LDS strides
// 280/152 (dword-stride 12 mod 32), histogram-based bucketing (atomics were
// serialized on one cacheline: ~120us).

#define N_ATOMS 65536
#define D_IN 256
#define D_HID 1024
#define D_OUT 256
#define TPS 1024   // max 64-row tiles per species (worst case: all rows one species)

typedef __attribute__((ext_vector_type(8))) short short8;
typedef __attribute__((ext_vector_type(4))) float float4e;

// ws layout (bytes):
//   [0, 256)           cnt[4] padded: cnt[s] at int offset s*16 (64B apart)
//   [256, 1048832)     bucket[4][65536] int
//   [1048832, 3145984) W1 swizzled bf16 fragments (4*256*1024)
//   [3145984, 5243136) W2 swizzled bf16 fragments (4*1024*256)
#define WS_BUCKET_OFF 256
#define WS_W1_OFF 1048832
#define WS_W2_OFF 3145984

__device__ __forceinline__ short f2bf(float f) {
  unsigned u = __builtin_bit_cast(unsigned, f);
  unsigned r = (u + 0x7FFFu + ((u >> 16) & 1u)) >> 16;   // round-to-nearest-even
  return (short)r;
}

// Swizzle W1/W2 fp32 -> bf16 MFMA B-fragment order; zero padded counters.
// B-frag (16x16x32): lane l holds B[k0 + 8*(l>>4) + j][nt*16 + (l&15)], j=0..7,
// each lane's 8 elems 16B-contiguous, lanes consecutive.
__global__ void prep_kernel(const float* __restrict__ W1, const float* __restrict__ W2,
                            short* __restrict__ w1sw, short* __restrict__ w2sw,
                            int* __restrict__ cnt) {
  int gid = blockIdx.x * 256 + threadIdx.x;   // 262144 threads
  if (gid < 64) cnt[gid] = 0;
  int lane = gid & 63;
  int lr = lane & 15;
  int lk = (lane >> 4) * 8;
  if (gid < 131072) {            // W1: [4][256][1024], NT=64, KS=8
    int ks = (gid >> 6) & 7;
    int nt = (gid >> 9) & 63;
    int s  = gid >> 15;
    const float* src = W1 + ((size_t)(s * 256 + ks * 32 + lk)) * 1024 + nt * 16 + lr;
    short8 v;
    for (int j = 0; j < 8; ++j) v[j] = f2bf(src[(size_t)j * 1024]);
    *(short8*)(w1sw + (size_t)gid * 8) = v;
  } else {                       // W2: [4][1024][256], NT=16, KS=32
    int g = gid - 131072;
    int kt = (g >> 6) & 31;
    int nt = (g >> 11) & 15;
    int s  = g >> 15;
    const float* src = W2 + ((size_t)(s * 1024 + kt * 32 + lk)) * 256 + nt * 16 + lr;
    short8 v;
    for (int j = 0; j < 8; ++j) v[j] = f2bf(src[(size_t)j * 256]);
    *(short8*)(w2sw + (size_t)g * 8) = v;
  }
}

// Bucket rows by species. Block-level histogram -> 4 atomics per block, to
// 64B-padded counters (4 independent serialization chains of ~256 each).
__global__ void count_fill_kernel(const int* __restrict__ species,
                                  int* __restrict__ cnt, int* __restrict__ bucket) {
  int tid = threadIdx.x;
  int i = blockIdx.x * 256 + tid;
  int s = species[i] & 3;
  int lane = tid & 63, wid = tid >> 6;
  __shared__ int wcnt[4][4];    // [wave][species]
  __shared__ int wbase[4][4];
  unsigned long long m0 = __ballot(s == 0);
  unsigned long long m1 = __ballot(s == 1);
  unsigned long long m2 = __ballot(s == 2);
  unsigned long long m3 = __ballot(s == 3);
  if (lane == 0) {
    wcnt[wid][0] = __popcll(m0); wcnt[wid][1] = __popcll(m1);
    wcnt[wid][2] = __popcll(m2); wcnt[wid][3] = __popcll(m3);
  }
  __syncthreads();
  if (tid < 4) {
    int ss = tid;
    int c0 = wcnt[0][ss], c1 = wcnt[1][ss], c2 = wcnt[2][ss], c3 = wcnt[3][ss];
    int base = atomicAdd(&cnt[ss * 16], c0 + c1 + c2 + c3);
    wbase[0][ss] = base;
    wbase[1][ss] = base + c0;
    wbase[2][ss] = base + c0 + c1;
    wbase[3][ss] = base + c0 + c1 + c2;
  }
  __syncthreads();
  unsigned long long below = (1ull << lane) - 1ull;
  int rank = 0;
  if (s == 0) rank = __popcll(m0 & below);
  if (s == 1) rank = __popcll(m1 & below);
  if (s == 2) rank = __popcll(m2 & below);
  if (s == 3) rank = __popcll(m3 & below);
  bucket[s * N_ATOMS + wbase[wid][s] + rank] = i;
}

// Fused per-tile MLP. Block = 256 threads (4 waves), tile = 64 rows.
// LDS: Xs 64x280 bf16 (35840B), Hs[2] 64x152 bf16 (38912B) -> 74752B, 2 blk/CU.
// Per hid-chunk c (8 chunks of 128), ONE barrier per chunk (Hs double-buffered):
//   GEMM1 (b1-frags preloaded in prior iter), prefetch b2-frags, silu->Hs[c&1],
//   barrier, prefetch next b1-frags (hidden under GEMM2 MFMA), GEMM2.
#define XS_STRIDE 280
#define HS_STRIDE 152
__global__ __launch_bounds__(256, 2) void fused_kernel(
    const float* __restrict__ x, const int* __restrict__ cntArr,
    const int* __restrict__ bucket, const short* __restrict__ w1sw,
    const short* __restrict__ w2sw, const float* __restrict__ b1,
    const float* __restrict__ b2, float* __restrict__ out) {
  int s = blockIdx.x >> 10;         // TPS = 1024
  int t = blockIdx.x & (TPS - 1);
  int cnt = cntArr[s * 16];
  int r0 = t * 64;
  if (r0 >= cnt) return;
  int nrows = min(64, cnt - r0);
  const int* buck = bucket + s * N_ATOMS + r0;

  __shared__ short Xs[64 * XS_STRIDE];
  __shared__ short Hs[2][64 * HS_STRIDE];

  int tid = threadIdx.x;

  // Stage gathered x tile -> bf16 LDS. 2048 8-elem groups / 256 threads.
  for (int i = 0; i < 8; ++i) {
    int id = tid + i * 256;
    int r = id >> 5;          // row 0..63
    int g = id & 31;          // 8-float group
    short8 v = {};
    if (r < nrows) {
      const float4* src = (const float4*)(x + (size_t)buck[r] * D_IN + g * 8);
      float4 f0 = src[0];
      float4 f1 = src[1];
      v[0] = f2bf(f0.x); v[1] = f2bf(f0.y); v[2] = f2bf(f0.z); v[3] = f2bf(f0.w);
      v[4] = f2bf(f1.x); v[5] = f2bf(f1.y); v[6] = f2bf(f1.z); v[7] = f2bf(f1.w);
    }
    *(short8*)(Xs + r * XS_STRIDE + g * 8) = v;
  }

  int lane = tid & 63;
  int wid = tid >> 6;
  int lr = lane & 15;          // A row / B,C col within 16-tile
  int lk = (lane >> 4) * 8;    // k base within 32-kstep
  int lq = (lane >> 4) * 4;    // C/D row base

  // Preload biases for this wave's columns (removes loads from the hot loop).
  float bias1[8][2];
  #pragma unroll
  for (int c = 0; c < 8; ++c)
    #pragma unroll
    for (int ct = 0; ct < 2; ++ct)
      bias1[c][ct] = b1[s * D_HID + c * 128 + wid * 32 + ct * 16 + lr];
  float bias2[4];
  #pragma unroll
  for (int ct = 0; ct < 4; ++ct)
    bias2[ct] = b2[s * D_OUT + wid * 64 + ct * 16 + lr];

  // Preload GEMM1 B-fragments for c=0 (16 batched loads, one latency exposure).
  short8 b1f[16];
  #pragma unroll
  for (int ks = 0; ks < 8; ++ks)
    #pragma unroll
    for (int ct = 0; ct < 2; ++ct) {
      int nt = 0 * 8 + wid * 2 + ct;
      b1f[ks * 2 + ct] = *(const short8*)(w1sw + ((size_t)((s * 64 + nt) * 8 + ks)) * 512 + lane * 8);
    }

  __syncthreads();   // Xs ready

  float4e accY[4][4] = {};     // 64 rows x 64 out cols per wave

  for (int c = 0; c < 8; ++c) {
    // ---- GEMM1: H chunk [64 x 128] = Xs @ W1[:, c*128..) ----
    float4e acc1[4][2] = {};
    #pragma unroll
    for (int ks = 0; ks < 8; ++ks) {
      short8 a[4];
      #pragma unroll
      for (int rt = 0; rt < 4; ++rt)
        a[rt] = *(const short8*)(Xs + (rt * 16 + lr) * XS_STRIDE + ks * 32 + lk);
      #pragma unroll
      for (int rt = 0; rt < 4; ++rt)
        #pragma unroll
        for (int ct = 0; ct < 2; ++ct)
          acc1[rt][ct] = __builtin_amdgcn_mfma_f32_16x16x32_bf16(a[rt], b1f[ks * 2 + ct], acc1[rt][ct], 0, 0, 0);
    }
    // ---- prefetch GEMM2 B-fragments (latency hidden under silu+barrier) ----
    short8 b2f[16];
    #pragma unroll
    for (int ks = 0; ks < 4; ++ks)
      #pragma unroll
      for (int ct = 0; ct < 4; ++ct) {
        int nt = wid * 4 + ct;
        int kt = c * 4 + ks;
        b2f[ks * 4 + ct] = *(const short8*)(w2sw + ((size_t)((s * 16 + nt) * 32 + kt)) * 512 + lane * 8);
      }
    // ---- bias + silu -> Hs[c&1] ----
    short* hsb = Hs[c & 1];
    #pragma unroll
    for (int ct = 0; ct < 2; ++ct) {
      int nloc = wid * 32 + ct * 16 + lr;
      float bias = bias1[c][ct];
      #pragma unroll
      for (int rt = 0; rt < 4; ++rt) {
        float4e v4 = acc1[rt][ct];
        #pragma unroll
        for (int q = 0; q < 4; ++q) {
          float pre = v4[q] + bias;
          float val = pre / (1.0f + __expf(-pre));     // silu
          hsb[(rt * 16 + lq + q) * HS_STRIDE + nloc] = f2bf(val);
        }
      }
    }
    __syncthreads();   // Hs[c&1] visible; prior readers of Hs[(c+1)&1] done
    // ---- prefetch next chunk's GEMM1 B-fragments (hidden under GEMM2 MFMA) ----
    if (c < 7) {
      #pragma unroll
      for (int ks = 0; ks < 8; ++ks)
        #pragma unroll
        for (int ct = 0; ct < 2; ++ct) {
          int nt = (c + 1) * 8 + wid * 2 + ct;
          b1f[ks * 2 + ct] = *(const short8*)(w1sw + ((size_t)((s * 64 + nt) * 8 + ks)) * 512 + lane * 8);
        }
    }
    // ---- GEMM2 partial: accY += H_chunk @ W2[c*128.., :] ----
    #pragma unroll
    for (int ks = 0; ks < 4; ++ks) {
      short8 a[4];
      #pragma unroll
      for (int rt = 0; rt < 4; ++rt)
        a[rt] = *(const short8*)(hsb + (rt * 16 + lr) * HS_STRIDE + ks * 32 + lk);
      #pragma unroll
      for (int rt = 0; rt < 4; ++rt)
        #pragma unroll
        for (int ct = 0; ct < 4; ++ct)
          accY[rt][ct] = __builtin_amdgcn_mfma_f32_16x16x32_bf16(a[rt], b2f[ks * 4 + ct], accY[rt][ct], 0, 0, 0);
    }
  }

  // ---- epilogue: scatter y + b2 to original rows ----
  #pragma unroll
  for (int ct = 0; ct < 4; ++ct) {
    int n = wid * 64 + ct * 16 + lr;
    float bias = bias2[ct];
    #pragma unroll
    for (int rt = 0; rt < 4; ++rt) {
      #pragma unroll
      for (int q = 0; q < 4; ++q) {
        int r = rt * 16 + lq + q;
        if (r < nrows)
          out[(size_t)buck[r] * D_OUT + n] = accY[rt][ct][q] + bias;
      }
    }
  }
}

extern "C" void kernel_launch(void* const* d_in, const int* in_sizes, int n_in,
                              void* d_out, int out_size, void* d_ws, size_t ws_size,
                              hipStream_t stream) {
  const float* x  = (const float*)d_in[0];
  const int* spc  = (const int*)d_in[1];
  const float* W1 = (const float*)d_in[2];
  const float* b1 = (const float*)d_in[3];
  const float* W2 = (const float*)d_in[4];
  const float* b2 = (const float*)d_in[5];
  float* out = (float*)d_out;

  int*   cnt    = (int*)d_ws;
  int*   bucket = (int*)((char*)d_ws + WS_BUCKET_OFF);
  short* w1sw   = (short*)((char*)d_ws + WS_W1_OFF);
  short* w2sw   = (short*)((char*)d_ws + WS_W2_OFF);

  prep_kernel<<<1024, 256, 0, stream>>>(W1, W2, w1sw, w2sw, cnt);
  count_fill_kernel<<<N_ATOMS / 256, 256, 0, stream>>>(spc, cnt, bucket);
  fused_kernel<<<4 * TPS, 256, 0, stream>>>(x, cnt, bucket, w1sw, w2sw, b1, b2, out);
}